// Round 1
// baseline (1653.119 us; speedup 1.0000x reference)
//
#include <hip/hip_runtime.h>
#include <hip/hip_bf16.h>

// Problem constants
#define M 8192          // B*H*W = 32*16*16
#define N 8192          // N_E
#define KDIM 512        // E_DIM

// Output layout (flat float32, reference return order)
static const size_t OFF_LOSS = 0;
static const size_t OFF_CONTRASTIVE = 1;
static const size_t OFF_KL = 2;
static const size_t OFF_PROB = 3;                                   // 8192*8192
static const size_t OFF_D    = OFF_PROB + (size_t)M * N;            // 67108867
static const size_t OFF_ZQ   = OFF_D + (size_t)M * N;               // 134217731
static const size_t OFF_PERP = OFF_ZQ + (size_t)M * KDIM;           // 138412035
static const size_t OFF_ENC  = OFF_PERP + 1;                        // 138412036
static const size_t OFF_IDX  = OFF_ENC + (size_t)M * N;             // 205520900

// ---------------------------------------------------------------------------
// Kernel 1: row norms. One wave (64 lanes) per row; rows 0..8191 = emb,
// rows 8192..16383 = z. Computes inv_norm = 1/||emb_j||, cbn = ||emb_j*inv||,
// zn = ||z_i||.
// ---------------------------------------------------------------------------
__global__ __launch_bounds__(256) void norms_kernel(
    const float* __restrict__ z, const float* __restrict__ emb,
    float* __restrict__ inv_norm, float* __restrict__ cbn,
    float* __restrict__ zn) {
  int g = blockIdx.x * 4 + (threadIdx.x >> 6);
  int lane = threadIdx.x & 63;
  if (g < N) {
    const float* p = emb + (size_t)g * KDIM + lane * 8;
    float4 v0 = *(const float4*)p;
    float4 v1 = *(const float4*)(p + 4);
    float s = v0.x * v0.x + v0.y * v0.y + v0.z * v0.z + v0.w * v0.w +
              v1.x * v1.x + v1.y * v1.y + v1.z * v1.z + v1.w * v1.w;
    #pragma unroll
    for (int off = 32; off > 0; off >>= 1) s += __shfl_down(s, off, 64);
    s = __shfl(s, 0, 64);
    float n = sqrtf(s);
    float inv = 1.0f / n;
    // norm of the rounded normalized row (cbn ~= 1, reference computes it)
    float c0 = v0.x * inv, c1 = v0.y * inv, c2 = v0.z * inv, c3 = v0.w * inv;
    float c4 = v1.x * inv, c5 = v1.y * inv, c6 = v1.z * inv, c7 = v1.w * inv;
    float s2 = c0 * c0 + c1 * c1 + c2 * c2 + c3 * c3 +
               c4 * c4 + c5 * c5 + c6 * c6 + c7 * c7;
    #pragma unroll
    for (int off = 32; off > 0; off >>= 1) s2 += __shfl_down(s2, off, 64);
    if (lane == 0) {
      inv_norm[g] = inv;
      cbn[g] = sqrtf(s2);
    }
  } else {
    int r = g - N;
    const float* p = z + (size_t)r * KDIM + lane * 8;
    float4 v0 = *(const float4*)p;
    float4 v1 = *(const float4*)(p + 4);
    float s = v0.x * v0.x + v0.y * v0.y + v0.z * v0.z + v0.w * v0.w +
              v1.x * v1.x + v1.y * v1.y + v1.z * v1.z + v1.w * v1.w;
    #pragma unroll
    for (int off = 32; off > 0; off >>= 1) s += __shfl_down(s, off, 64);
    if (lane == 0) zn[r] = sqrtf(s);
  }
}

// ---------------------------------------------------------------------------
// Kernel 2: fp32 SGEMM  d[i][j] = dot(z_i, emb_j * inv_norm_j)
//                                  / (zn_i * cbn_j + 1e-6)
// 128x128 tile per 256-thread block, BK=8, 8x8 micro-tile per thread.
// Scalar epilogue stores (d region is misaligned mod 16B).
// ---------------------------------------------------------------------------
#define BM 128
#define BN 128
#define BK 8
__global__ __launch_bounds__(256) void gemm_kernel(
    const float* __restrict__ z, const float* __restrict__ emb,
    const float* __restrict__ inv_norm, const float* __restrict__ cbn,
    const float* __restrict__ zn, float* __restrict__ dout) {
  __shared__ __align__(16) float As[BK][BM + 4];
  __shared__ __align__(16) float Bs[BK][BN + 4];

  const int tid = threadIdx.x;
  const int tx = tid & 15;
  const int ty = tid >> 4;
  const int row0 = blockIdx.y * BM;
  const int col0 = blockIdx.x * BN;

  // staging-load indices: 256 threads load 128 rows x 8 k (1 float4 each)
  const int lr = tid >> 1;          // 0..127
  const int lk = (tid & 1) * 4;     // 0 or 4
  const float* Aptr = z + (size_t)(row0 + lr) * KDIM + lk;
  const float* Bptr = emb + (size_t)(col0 + lr) * KDIM + lk;
  const float binv = inv_norm[col0 + lr];

  float acc[8][8];
  #pragma unroll
  for (int r = 0; r < 8; r++)
    #pragma unroll
    for (int c = 0; c < 8; c++) acc[r][c] = 0.0f;

  for (int kt = 0; kt < KDIM; kt += BK) {
    float4 av = *(const float4*)(Aptr + kt);
    float4 bv = *(const float4*)(Bptr + kt);
    bv.x *= binv; bv.y *= binv; bv.z *= binv; bv.w *= binv;
    __syncthreads();
    As[lk + 0][lr] = av.x; As[lk + 1][lr] = av.y;
    As[lk + 2][lr] = av.z; As[lk + 3][lr] = av.w;
    Bs[lk + 0][lr] = bv.x; Bs[lk + 1][lr] = bv.y;
    Bs[lk + 2][lr] = bv.z; Bs[lk + 3][lr] = bv.w;
    __syncthreads();
    #pragma unroll
    for (int kk = 0; kk < BK; kk++) {
      float a8[8], b8[8];
      *(float4*)&a8[0] = *(const float4*)&As[kk][ty * 8];
      *(float4*)&a8[4] = *(const float4*)&As[kk][ty * 8 + 4];
      *(float4*)&b8[0] = *(const float4*)&Bs[kk][tx * 8];
      *(float4*)&b8[4] = *(const float4*)&Bs[kk][tx * 8 + 4];
      #pragma unroll
      for (int r = 0; r < 8; r++)
        #pragma unroll
        for (int c = 0; c < 8; c++) acc[r][c] += a8[r] * b8[c];
    }
  }

  const int rbase = row0 + ty * 8;
  const int cbase = col0 + tx * 8;
  float znr[8], cnc[8];
  #pragma unroll
  for (int r = 0; r < 8; r++) znr[r] = zn[rbase + r];
  #pragma unroll
  for (int c = 0; c < 8; c++) cnc[c] = cbn[cbase + c];
  #pragma unroll
  for (int r = 0; r < 8; r++) {
    size_t o = (size_t)(rbase + r) * N + cbase;
    #pragma unroll
    for (int c = 0; c < 8; c++) {
      dout[o + c] = acc[r][c] / (znr[r] * cnc[c] + 1e-6f);
    }
  }
}

// ---------------------------------------------------------------------------
// Kernel 3: per-row argmax + softmax + one-hot scatter + z_q gather +
// histogram + cosine accumulation. One 256-thread block per row; the row
// (8192 floats) lives in 32 regs/thread.
// ---------------------------------------------------------------------------
__global__ __launch_bounds__(256) void row_kernel(
    const float* __restrict__ dmat, float* __restrict__ prob,
    float* __restrict__ enc, float* __restrict__ zq,
    float* __restrict__ idxout, const float* __restrict__ emb,
    const float* __restrict__ inv_norm, const float* __restrict__ cbn,
    const float* __restrict__ zn, int* __restrict__ counts,
    float* __restrict__ cos_sum) {
  const int row = blockIdx.x;
  const int tid = threadIdx.x;
  const float* drow = dmat + (size_t)row * N;

  float v[32];
  float m = -1e30f;
  int mi = 0;
  #pragma unroll
  for (int u = 0; u < 32; u++) {
    int col = u * 256 + tid;
    float x = drow[col];
    v[u] = x;
    if (x > m) { m = x; mi = col; }   // strict > keeps first occurrence
  }

  __shared__ float sM[256];
  __shared__ int sI[256];
  sM[tid] = m; sI[tid] = mi;
  __syncthreads();
  for (int s = 128; s > 0; s >>= 1) {
    if (tid < s) {
      float om = sM[tid + s]; int oi = sI[tid + s];
      if (om > sM[tid] || (om == sM[tid] && oi < sI[tid])) {
        sM[tid] = om; sI[tid] = oi;
      }
    }
    __syncthreads();
  }
  const float maxv = sM[0];
  const int best = sI[0];
  __syncthreads();

  float se = 0.0f;
  #pragma unroll
  for (int u = 0; u < 32; u++) se += expf(v[u] - maxv);
  sM[tid] = se;
  __syncthreads();
  for (int s = 128; s > 0; s >>= 1) {
    if (tid < s) sM[tid] += sM[tid + s];
    __syncthreads();
  }
  const float invsum = 1.0f / sM[0];

  float* prow = prob + (size_t)row * N;
  #pragma unroll
  for (int u = 0; u < 32; u++) {
    int col = u * 256 + tid;
    prow[col] = expf(v[u] - maxv) * invsum;
  }

  // z_q row = emb[best] * inv_norm[best]
  const float sc = inv_norm[best];
  const float* erow = emb + (size_t)best * KDIM;
  float* zrow = zq + (size_t)row * KDIM;
  for (int j = tid; j < KDIM; j += 256) zrow[j] = erow[j] * sc;

  if (tid == 0) {
    enc[(size_t)row * N + best] = 1.0f;
    idxout[row] = (float)best;
    atomicAdd(&counts[best], 1);
    float znr = zn[row], cn = cbn[best];
    float dotv = maxv * (znr * cn + 1e-6f);     // recover raw dot from scaled d
    float cosv = dotv / (fmaxf(znr, 1e-8f) * fmaxf(cn, 1e-8f));
    atomicAdd(cos_sum, cosv);
  }
}

// ---------------------------------------------------------------------------
// Kernel 4: scalar finalize — KL, perplexity, loss.
// ---------------------------------------------------------------------------
__global__ __launch_bounds__(256) void finalize_kernel(
    const int* __restrict__ counts, const float* __restrict__ cos_sum,
    float* __restrict__ out) {
  __shared__ float sKL[256];
  __shared__ float sEnt[256];
  const int tid = threadIdx.x;
  float kl = 0.0f, ent = 0.0f;
  for (int i = tid; i < N; i += 256) {
    float e = (float)counts[i] * (1.0f / (float)M);
    kl += e * logf((1.0f / (float)N) / (e + 1e-6f));
    ent += e * logf(e + 1e-6f);
  }
  sKL[tid] = kl; sEnt[tid] = ent;
  __syncthreads();
  for (int s = 128; s > 0; s >>= 1) {
    if (tid < s) { sKL[tid] += sKL[tid + s]; sEnt[tid] += sEnt[tid + s]; }
    __syncthreads();
  }
  if (tid == 0) {
    float mc = *cos_sum * (1.0f / (float)M);
    out[OFF_LOSS] = (1.0f - mc) + 0.25f * (1.0f - mc);
    out[OFF_CONTRASTIVE] = 0.0f;
    out[OFF_KL] = -sKL[0];
    out[OFF_PERP] = expf(-sEnt[0]);
  }
}

extern "C" void kernel_launch(void* const* d_in, const int* in_sizes, int n_in,
                              void* d_out, int out_size, void* d_ws,
                              size_t ws_size, hipStream_t stream) {
  const float* z = (const float*)d_in[0];
  const float* emb = (const float*)d_in[1];
  float* out = (float*)d_out;

  // workspace layout (floats): inv_norm[8192] | cbn[8192] | zn[8192] |
  //                            counts[8192] (int) | cos_sum[1]
  float* wsf = (float*)d_ws;
  float* inv_norm = wsf;
  float* cbn = wsf + 8192;
  float* zn = wsf + 16384;
  int* counts = (int*)(wsf + 24576);
  float* cos_sum = wsf + 24576 + 8192;

  // zero histogram + cos accumulator, and the one-hot output region
  hipMemsetAsync(counts, 0, (8192 + 1) * sizeof(float), stream);
  hipMemsetAsync(out + OFF_ENC, 0, (size_t)M * N * sizeof(float), stream);

  norms_kernel<<<(2 * N) / 4, 256, 0, stream>>>(z, emb, inv_norm, cbn, zn);

  dim3 g2(N / BN, M / BM);
  gemm_kernel<<<g2, 256, 0, stream>>>(z, emb, inv_norm, cbn, zn, out + OFF_D);

  row_kernel<<<M, 256, 0, stream>>>(out + OFF_D, out + OFF_PROB, out + OFF_ENC,
                                    out + OFF_ZQ, out + OFF_IDX, emb, inv_norm,
                                    cbn, zn, counts, cos_sum);

  finalize_kernel<<<1, 256, 0, stream>>>(counts, cos_sum, out);
}